// Round 12
// baseline (329.206 us; speedup 1.0000x reference)
//
#include <hip/hip_runtime.h>
#include <hip/hip_fp16.h>

#define NN 100000
#define NE 1200000
#define NBUK ((NN + 127) / 128)   // 782
#define NCHUNK 128                // blocks in pass A

typedef _Float16 h8 __attribute__((ext_vector_type(8)));
typedef float f32x4 __attribute__((ext_vector_type(4)));

// ---------------- bucketed CSR build ----------------
__global__ __launch_bounds__(1024) void k_zerob(int* bcnt) {
    int i = threadIdx.x;
    if (i <= NBUK) bcnt[i] = 0;
}

__global__ __launch_bounds__(256) void k_bhist(const int* __restrict__ col, int* __restrict__ bcnt) {
    __shared__ int lh[NBUK];
    for (int i = threadIdx.x; i < NBUK; i += 256) lh[i] = 0;
    __syncthreads();
    for (int e = blockIdx.x * 256 + threadIdx.x; e < NE; e += 256 * 256)
        atomicAdd(&lh[col[e] >> 7], 1);
    __syncthreads();
    for (int i = threadIdx.x; i < NBUK; i += 256) {
        int v = lh[i];
        if (v) atomicAdd(&bcnt[i], v);
    }
}

__global__ __launch_bounds__(1024) void k_bscan(int* __restrict__ bcnt, int* __restrict__ bcur) {
    __shared__ int s[1024];
    int tid = threadIdx.x;
    int v = (tid < NBUK) ? bcnt[tid] : 0;
    s[tid] = v;
    __syncthreads();
    #pragma unroll
    for (int d = 1; d < 1024; d <<= 1) {
        int t = (tid >= d) ? s[tid - d] : 0;
        __syncthreads();
        s[tid] += t;
        __syncthreads();
    }
    if (tid < NBUK) {
        int excl = s[tid] - v;
        bcnt[tid] = excl;
        bcur[tid] = excl;
    }
    if (tid == 0) bcnt[NBUK] = NE;
}

__global__ __launch_bounds__(256) void k_bucket(const int* __restrict__ row,
                                                const int* __restrict__ col,
                                                int* __restrict__ bcur,
                                                unsigned* __restrict__ tmp) {
    __shared__ int lh[NBUK];
    const int tid = threadIdx.x;
    const int per = (NE + NCHUNK - 1) / NCHUNK;
    const int e0 = blockIdx.x * per;
    const int e1 = (e0 + per < NE) ? (e0 + per) : NE;
    for (int i = tid; i < NBUK; i += 256) lh[i] = 0;
    __syncthreads();
    for (int e = e0 + tid; e < e1; e += 256)
        atomicAdd(&lh[col[e] >> 7], 1);
    __syncthreads();
    for (int b = tid; b < NBUK; b += 256) {
        int c = lh[b];
        if (c) lh[b] = atomicAdd(&bcur[b], c);
    }
    __syncthreads();
    for (int e = e0 + tid; e < e1; e += 256) {
        int c = col[e], r = row[e];
        int pos = atomicAdd(&lh[c >> 7], 1);
        tmp[pos] = ((unsigned)r << 7) | (unsigned)(c & 127);
    }
}

__global__ __launch_bounds__(256) void k_build(const unsigned* __restrict__ tmp,
                                               const int* __restrict__ bbase,
                                               int* __restrict__ off,
                                               float* __restrict__ dinv,
                                               int* __restrict__ csr_row) {
    __shared__ int cnt[128], s[128], cur[128];
    const int b = blockIdx.x, tid = threadIdx.x;
    const int colBase = b << 7;
    const int nCols = (NN - colBase < 128) ? (NN - colBase) : 128;
    const int seg0 = bbase[b], seg1 = bbase[b + 1];
    if (tid < 128) cnt[tid] = 0;
    __syncthreads();
    for (int i = seg0 + tid; i < seg1; i += 256)
        atomicAdd(&cnt[tmp[i] & 127], 1);
    __syncthreads();
    if (tid < 128) s[tid] = cnt[tid];
    __syncthreads();
    #pragma unroll
    for (int d = 1; d < 128; d <<= 1) {
        int t = (tid < 128 && tid >= d) ? s[tid - d] : 0;
        __syncthreads();
        if (tid < 128) s[tid] += t;
        __syncthreads();
    }
    if (tid < nCols) {
        int exc = seg0 + s[tid] - cnt[tid];
        off[colBase + tid] = exc;
        cur[tid] = exc;
        dinv[colBase + tid] = rsqrtf((float)cnt[tid] + 1.0f);
    }
    if (b == 0 && tid == 0) off[NN] = NE;
    __syncthreads();
    for (int i = seg0 + tid; i < seg1; i += 256) {
        unsigned v = tmp[i];
        int pos = atomicAdd(&cur[v & 127u], 1);
        csr_row[pos] = (int)(v >> 7);
    }
}

// ---------------- proj GEMM (D=128): B-frags direct from global, out fp16 hA + byp ----------------
__global__ __launch_bounds__(256) void k_gemmP(const float* __restrict__ X,
                                               const float* __restrict__ W,
                                               const float* __restrict__ bias,
                                               _Float16* __restrict__ Yh,
                                               const float* __restrict__ bypW,
                                               const float* __restrict__ bypb,
                                               float* __restrict__ bypOut,
                                               int n_nodes) {
    constexpr int D = 128, RS = D + 8, KS = D / 32;
    __shared__ _Float16 Xh[64 * RS];     // 17.4 KB -> 8 blocks/CU
    __shared__ float BWs[387];
    const int tid = threadIdx.x;
    const int n0 = blockIdx.x * 64;

    for (int i = tid; i < 64 * (D / 8); i += 256) {
        int nl = i / (D / 8), d8 = (i % (D / 8)) * 8;
        int n = n0 + nl; if (n >= n_nodes) n = n_nodes - 1;
        const float4* xp = (const float4*)&X[(size_t)n * D + d8];
        float4 x0 = xp[0], x1 = xp[1];
        h8 h = { (_Float16)x0.x, (_Float16)x0.y, (_Float16)x0.z, (_Float16)x0.w,
                 (_Float16)x1.x, (_Float16)x1.y, (_Float16)x1.z, (_Float16)x1.w };
        *(h8*)&Xh[nl * RS + d8] = h;
    }
    for (int idx = tid; idx < 387; idx += 256)
        BWs[idx] = (idx < 384) ? bypW[idx] : bypb[idx - 384];
    __syncthreads();

    const int wid = tid >> 6, lane = tid & 63;
    const int lm = lane & 15, lq = lane >> 4;
    const int mBase = wid * 16;

    // B-fragments straight from global W (L2-hot)
    h8 bfrag[4][KS];
    #pragma unroll
    for (int t = 0; t < 4; ++t)
        #pragma unroll
        for (int s = 0; s < KS; ++s) {
            const float4* wp = (const float4*)&W[(t * 16 + lm) * D + s * 32 + lq * 8];
            float4 w0 = wp[0], w1 = wp[1];
            bfrag[t][s] = (h8){ (_Float16)w0.x, (_Float16)w0.y, (_Float16)w0.z, (_Float16)w0.w,
                                (_Float16)w1.x, (_Float16)w1.y, (_Float16)w1.z, (_Float16)w1.w };
        }

    f32x4 acc[4] = {};
    #pragma unroll
    for (int s = 0; s < KS; ++s) {
        h8 a = *(const h8*)&Xh[(mBase + lm) * RS + s * 32 + lq * 8];
        #pragma unroll
        for (int t = 0; t < 4; ++t)
            acc[t] = __builtin_amdgcn_mfma_f32_16x16x32_f16(a, bfrag[t][s], acc[t], 0, 0, 0);
    }

    float bb[4];
    #pragma unroll
    for (int t = 0; t < 4; ++t) bb[t] = bias[t * 16 + lm];
    const int nodeBase = n0 + mBase + lq * 4;
    #pragma unroll
    for (int r = 0; r < 4; ++r) {
        int node = nodeBase + r;
        if (node < n_nodes) {
            #pragma unroll
            for (int t = 0; t < 4; ++t)
                Yh[(size_t)node * 64 + t * 16 + lm] = (_Float16)(acc[t][r] + bb[t]);
        }
    }
    if (tid < 192) {
        int nl2 = tid & 63, o = tid >> 6;
        int n = n0 + nl2;
        int nc = (n < n_nodes) ? n : (n_nodes - 1);
        const float4* xr = (const float4*)&X[(size_t)nc * D];
        float4 a4 = make_float4(0.f, 0.f, 0.f, 0.f);
        #pragma unroll 8
        for (int i = 0; i < D / 4; i++) {
            float4 v = xr[i];
            const float4 wv = *(const float4*)&BWs[o * 128 + 4 * i];
            a4.x += v.x * wv.x; a4.y += v.y * wv.y;
            a4.z += v.z * wv.z; a4.w += v.w * wv.w;
        }
        float b = BWs[384 + o] + a4.x + a4.y + a4.z + a4.w;
        if (n < n_nodes) bypOut[n * 3 + o] = b;
    }
}

// ---------------- conv GEMM (D=64): fp16 A straight copy, Wh LDS, out fp16 * dinv ----------------
__global__ __launch_bounds__(256) void k_gemmC(const _Float16* __restrict__ Xhg,
                                               const float* __restrict__ W,
                                               const float* __restrict__ dinv,
                                               _Float16* __restrict__ Yh,
                                               int n_nodes) {
    constexpr int D = 64, RS = D + 8, KS = D / 32;
    __shared__ _Float16 Xh[64 * RS];     // 9.2 KB
    __shared__ _Float16 Wh[64 * RS];     // 9.2 KB
    const int tid = threadIdx.x;
    const int n0 = blockIdx.x * 64;

    for (int i = tid; i < 64 * (D / 8); i += 256) {
        int j = i / (D / 8), d8 = (i % (D / 8)) * 8;
        const float4* wp = (const float4*)&W[j * D + d8];
        float4 w0 = wp[0], w1 = wp[1];
        h8 h = { (_Float16)w0.x, (_Float16)w0.y, (_Float16)w0.z, (_Float16)w0.w,
                 (_Float16)w1.x, (_Float16)w1.y, (_Float16)w1.z, (_Float16)w1.w };
        *(h8*)&Wh[j * RS + d8] = h;
    }
    for (int i = tid; i < 64 * (D / 8); i += 256) {
        int nl = i / (D / 8), d8 = (i % (D / 8)) * 8;
        int n = n0 + nl; if (n >= n_nodes) n = n_nodes - 1;
        *(h8*)&Xh[nl * RS + d8] = *(const h8*)&Xhg[(size_t)n * D + d8];   // straight copy
    }
    __syncthreads();

    const int wid = tid >> 6, lane = tid & 63;
    const int lm = lane & 15, lq = lane >> 4;
    const int mBase = wid * 16;

    h8 bfrag[4][KS];
    #pragma unroll
    for (int t = 0; t < 4; ++t)
        #pragma unroll
        for (int s = 0; s < KS; ++s)
            bfrag[t][s] = *(const h8*)&Wh[(t * 16 + lm) * RS + s * 32 + lq * 8];

    f32x4 acc[4] = {};
    #pragma unroll
    for (int s = 0; s < KS; ++s) {
        h8 a = *(const h8*)&Xh[(mBase + lm) * RS + s * 32 + lq * 8];
        #pragma unroll
        for (int t = 0; t < 4; ++t)
            acc[t] = __builtin_amdgcn_mfma_f32_16x16x32_f16(a, bfrag[t][s], acc[t], 0, 0, 0);
    }

    const int nodeBase = n0 + mBase + lq * 4;
    #pragma unroll
    for (int r = 0; r < 4; ++r) {
        int node = nodeBase + r;
        if (node < n_nodes) {
            float sdv = dinv[node];
            #pragma unroll
            for (int t = 0; t < 4; ++t)
                Yh[(size_t)node * 64 + t * 16 + lm] = (_Float16)(acc[t][r] * sdv);
        }
    }
}

// ---------------- pull-aggregation: 8 nodes/wave, 8 lanes/node; hA fp16 ----------------
template<bool RES, bool HEAD>
__global__ __launch_bounds__(256) void k_gather(const _Float16* __restrict__ hBh,
                                                const float* __restrict__ dinv,
                                                const int* __restrict__ off,
                                                const int* __restrict__ csr_row,
                                                const float* __restrict__ convb,
                                                const float* __restrict__ bng,
                                                const float* __restrict__ bnb,
                                                _Float16* __restrict__ hA,
                                                const float* __restrict__ byp,
                                                const float* __restrict__ headW,
                                                const float* __restrict__ headb,
                                                float* __restrict__ out) {
    __shared__ float HWs[HEAD ? 204 : 1];
    const int tid = threadIdx.x;
    if constexpr (HEAD) {
        for (int i = tid; i < 204; i += 256)
            HWs[i] = (i < 201) ? headW[i] : headb[i - 201];
        __syncthreads();
    }
    const int wid = tid >> 6, lane = tid & 63;
    const int n = blockIdx.x * 32 + wid * 8 + (lane >> 3);   // grid = NN/32 exactly
    const int oct = lane & 7;
    const int f0 = oct * 8;

    const int e0 = off[n], eEnd = off[n + 1];
    const int deg = eEnd - e0;
    int m = deg;
    #pragma unroll
    for (int mask = 8; mask < 64; mask <<= 1) {
        int o = __shfl_xor(m, mask, 64);
        m = (o > m) ? o : m;
    }

    h8 acch = *(const h8*)(hBh + ((size_t)n << 6) + f0);   // self-loop term
    const h8 zero = (h8)(_Float16)0;
    for (int it = 0; it < m; it += 2) {
        bool v0 = it < deg, v1 = it + 1 < deg;
        int i0 = e0 + it, i1 = i0 + 1;
        int r0 = csr_row[v0 ? i0 : 0];
        int r1 = csr_row[v1 ? i1 : 0];
        h8 raw0 = *(const h8*)(hBh + ((size_t)r0 << 6) + f0);
        h8 raw1 = *(const h8*)(hBh + ((size_t)r1 << 6) + f0);
        acch = acch + (v0 ? raw0 : zero);
        acch = acch + (v1 ? raw1 : zero);
    }

    const float dv = dinv[n];
    const float bnscale = rsqrtf(1.0f + 1e-5f);
    const float4 cb0 = *(const float4*)&convb[f0], cb1 = *(const float4*)&convb[f0 + 4];
    const float4 g0  = *(const float4*)&bng[f0],  g1  = *(const float4*)&bng[f0 + 4];
    const float4 b0_ = *(const float4*)&bnb[f0],  b1_ = *(const float4*)&bnb[f0 + 4];
    const float cb[8] = { cb0.x, cb0.y, cb0.z, cb0.w, cb1.x, cb1.y, cb1.z, cb1.w };
    const float gg[8] = { g0.x, g0.y, g0.z, g0.w, g1.x, g1.y, g1.z, g1.w };
    const float bb[8] = { b0_.x, b0_.y, b0_.z, b0_.w, b1_.x, b1_.y, b1_.z, b1_.w };
    float v[8];
    #pragma unroll
    for (int j = 0; j < 8; ++j)
        v[j] = fmaxf(((float)acch[j] * dv + cb[j]) * (gg[j] * bnscale) + bb[j], 0.0f);

    if constexpr (!HEAD) {
        size_t o = ((size_t)n << 6) + f0;
        if constexpr (RES) {
            h8 old = *(const h8*)&hA[o];
            #pragma unroll
            for (int j = 0; j < 8; ++j) v[j] += (float)old[j];
        }
        h8 res = { (_Float16)v[0], (_Float16)v[1], (_Float16)v[2], (_Float16)v[3],
                   (_Float16)v[4], (_Float16)v[5], (_Float16)v[6], (_Float16)v[7] };
        *(h8*)&hA[o] = res;
    } else {
        float p[3];
        #pragma unroll
        for (int o = 0; o < 3; ++o) {
            float t = 0.f;
            #pragma unroll
            for (int j = 0; j < 8; ++j) t += v[j] * HWs[o * 67 + f0 + j];
            p[o] = t;
        }
        #pragma unroll
        for (int mask = 1; mask < 8; mask <<= 1) {
            #pragma unroll
            for (int o = 0; o < 3; ++o) p[o] += __shfl_xor(p[o], mask, 64);
        }
        if (oct == 0) {
            float by0 = byp[n * 3], by1 = byp[n * 3 + 1], by2 = byp[n * 3 + 2];
            #pragma unroll
            for (int o = 0; o < 3; ++o)
                p[o] += by0 * HWs[o * 67 + 64] + by1 * HWs[o * 67 + 65] + by2 * HWs[o * 67 + 66]
                      + HWs[201 + o];
            float kappa = fminf(fmaxf(p[0] * 5.0f + 2.5f, 0.2f), 10.0f);
            float tau   = fminf(fmaxf(p[2] + 0.5f, 0.05f), 2.0f);
            out[(size_t)n * 3]     = kappa;
            out[(size_t)n * 3 + 1] = p[1];
            out[(size_t)n * 3 + 2] = tau;
        }
    }
}

extern "C" void kernel_launch(void* const* d_in, const int* in_sizes, int n_in,
                              void* d_out, int out_size, void* d_ws, size_t ws_size,
                              hipStream_t stream) {
    const float* x     = (const float*)d_in[0];
    const int*   ei    = (const int*)d_in[1];
    const int*   row   = ei;
    const int*   col   = ei + NE;
    const float* projW = (const float*)d_in[2];
    const float* projb = (const float*)d_in[3];
    const float* convW[3] = { (const float*)d_in[4], (const float*)d_in[8],  (const float*)d_in[12] };
    const float* convb[3] = { (const float*)d_in[5], (const float*)d_in[9],  (const float*)d_in[13] };
    const float* bng[3]   = { (const float*)d_in[6], (const float*)d_in[10], (const float*)d_in[14] };
    const float* bnb[3]   = { (const float*)d_in[7], (const float*)d_in[11], (const float*)d_in[15] };
    const float* bypW  = (const float*)d_in[16];
    const float* bypb  = (const float*)d_in[17];
    const float* headW = (const float*)d_in[18];
    const float* headb = (const float*)d_in[19];
    float* out = (float*)d_out;

    float*    ws   = (float*)d_ws;
    float*    dinv = ws;                                   // 102400 floats
    _Float16* hAh  = (_Float16*)(ws + 102400);             // NN*64 fp16
    _Float16* hBh  = hAh + (size_t)NN * 64;                // NN*64 fp16
    float*    byp  = (float*)(hBh + (size_t)NN * 64);      // NN*3 (+pad)
    int*      off     = (int*)(byp + 300032);              // NN+1 (pad 100096)
    int*      csr_row = off + 100096;                      // NE
    int*      bcnt    = csr_row + NE;                      // NBUK+1 (pad 784)
    int*      bcur    = bcnt + 784;                        // NBUK
    unsigned* tmp     = (unsigned*)hAh;                    // aliases hAh (consumed before proj)

    // bucketed CSR build (+dinv +off)
    k_zerob<<<1, 1024, 0, stream>>>(bcnt);
    k_bhist<<<256, 256, 0, stream>>>(col, bcnt);
    k_bscan<<<1, 1024, 0, stream>>>(bcnt, bcur);
    k_bucket<<<NCHUNK, 256, 0, stream>>>(row, col, bcur, tmp);
    k_build<<<NBUK, 256, 0, stream>>>(tmp, bcnt, off, dinv, csr_row);

    // proj: hAh = fp16(x @ projW.T + projb), byp = x @ bypW.T + bypb
    k_gemmP<<<(NN + 63) / 64, 256, 0, stream>>>(x, projW, projb, hAh, bypW, bypb, byp, NN);

    for (int l = 0; l < 3; l++) {
        // hBh = fp16((hAh @ convW.T) * dinv)
        k_gemmC<<<(NN + 63) / 64, 256, 0, stream>>>(hAh, convW[l], dinv, hBh, NN);
        if (l < 2)
            k_gather<true, false><<<NN / 32, 256, 0, stream>>>(
                hBh, dinv, off, csr_row, convb[l], bng[l], bnb[l], hAh,
                nullptr, nullptr, nullptr, nullptr);
        else
            k_gather<false, true><<<NN / 32, 256, 0, stream>>>(
                hBh, dinv, off, csr_row, convb[l], bng[l], bnb[l], nullptr,
                byp, headW, headb, out);
    }
}

// Round 13
// 293.294 us; speedup vs baseline: 1.1224x; 1.1224x over previous
//
#include <hip/hip_runtime.h>
#include <hip/hip_fp16.h>

#define NN 100000
#define NE 1200000
#define NBUK ((NN + 127) / 128)   // 782
#define NCHUNK 128                // blocks in pass A

typedef _Float16 h8 __attribute__((ext_vector_type(8)));
typedef float f32x4 __attribute__((ext_vector_type(4)));

// ---------------- bucketed CSR build ----------------
__global__ __launch_bounds__(1024) void k_zerob(int* bcnt) {
    int i = threadIdx.x;
    if (i <= NBUK) bcnt[i] = 0;
}

__global__ __launch_bounds__(256) void k_bhist(const int* __restrict__ col, int* __restrict__ bcnt) {
    __shared__ int lh[NBUK];
    for (int i = threadIdx.x; i < NBUK; i += 256) lh[i] = 0;
    __syncthreads();
    for (int e = blockIdx.x * 256 + threadIdx.x; e < NE; e += 256 * 256)
        atomicAdd(&lh[col[e] >> 7], 1);
    __syncthreads();
    for (int i = threadIdx.x; i < NBUK; i += 256) {
        int v = lh[i];
        if (v) atomicAdd(&bcnt[i], v);
    }
}

__global__ __launch_bounds__(1024) void k_bscan(int* __restrict__ bcnt, int* __restrict__ bcur) {
    __shared__ int s[1024];
    int tid = threadIdx.x;
    int v = (tid < NBUK) ? bcnt[tid] : 0;
    s[tid] = v;
    __syncthreads();
    #pragma unroll
    for (int d = 1; d < 1024; d <<= 1) {
        int t = (tid >= d) ? s[tid - d] : 0;
        __syncthreads();
        s[tid] += t;
        __syncthreads();
    }
    if (tid < NBUK) {
        int excl = s[tid] - v;
        bcnt[tid] = excl;
        bcur[tid] = excl;
    }
    if (tid == 0) bcnt[NBUK] = NE;
}

__global__ __launch_bounds__(256) void k_bucket(const int* __restrict__ row,
                                                const int* __restrict__ col,
                                                int* __restrict__ bcur,
                                                unsigned* __restrict__ tmp) {
    __shared__ int lh[NBUK];
    const int tid = threadIdx.x;
    const int per = (NE + NCHUNK - 1) / NCHUNK;
    const int e0 = blockIdx.x * per;
    const int e1 = (e0 + per < NE) ? (e0 + per) : NE;
    for (int i = tid; i < NBUK; i += 256) lh[i] = 0;
    __syncthreads();
    for (int e = e0 + tid; e < e1; e += 256)
        atomicAdd(&lh[col[e] >> 7], 1);
    __syncthreads();
    for (int b = tid; b < NBUK; b += 256) {
        int c = lh[b];
        if (c) lh[b] = atomicAdd(&bcur[b], c);
    }
    __syncthreads();
    for (int e = e0 + tid; e < e1; e += 256) {
        int c = col[e], r = row[e];
        int pos = atomicAdd(&lh[c >> 7], 1);
        tmp[pos] = ((unsigned)r << 7) | (unsigned)(c & 127);
    }
}

__global__ __launch_bounds__(256) void k_build(const unsigned* __restrict__ tmp,
                                               const int* __restrict__ bbase,
                                               int* __restrict__ off,
                                               float* __restrict__ dinv,
                                               int* __restrict__ csr_row) {
    __shared__ int cnt[128], s[128], cur[128];
    const int b = blockIdx.x, tid = threadIdx.x;
    const int colBase = b << 7;
    const int nCols = (NN - colBase < 128) ? (NN - colBase) : 128;
    const int seg0 = bbase[b], seg1 = bbase[b + 1];
    if (tid < 128) cnt[tid] = 0;
    __syncthreads();
    for (int i = seg0 + tid; i < seg1; i += 256)
        atomicAdd(&cnt[tmp[i] & 127], 1);
    __syncthreads();
    if (tid < 128) s[tid] = cnt[tid];
    __syncthreads();
    #pragma unroll
    for (int d = 1; d < 128; d <<= 1) {
        int t = (tid < 128 && tid >= d) ? s[tid - d] : 0;
        __syncthreads();
        if (tid < 128) s[tid] += t;
        __syncthreads();
    }
    if (tid < nCols) {
        int exc = seg0 + s[tid] - cnt[tid];
        off[colBase + tid] = exc;
        cur[tid] = exc;
        dinv[colBase + tid] = rsqrtf((float)cnt[tid] + 1.0f);
    }
    if (b == 0 && tid == 0) off[NN] = NE;
    __syncthreads();
    for (int i = seg0 + tid; i < seg1; i += 256) {
        unsigned v = tmp[i];
        int pos = atomicAdd(&cur[v & 127u], 1);
        csr_row[pos] = (int)(v >> 7);
    }
}

// ---------------- proj GEMM (D=128): LDS-staged W, byp folded as 5th MFMA n-tile ----------------
__global__ __launch_bounds__(256) void k_gemmP(const float* __restrict__ X,
                                               const float* __restrict__ W,
                                               const float* __restrict__ bias,
                                               _Float16* __restrict__ Yh,
                                               const float* __restrict__ bypW,
                                               const float* __restrict__ bypb,
                                               float* __restrict__ bypOut,
                                               int n_nodes) {
    constexpr int D = 128, RS = D + 8, KS = D / 32;
    __shared__ _Float16 Xh[64 * RS];     // 17.4 KB
    __shared__ _Float16 Wh[64 * RS];     // 17.4 KB
    const int tid = threadIdx.x;
    const int n0 = blockIdx.x * 64;

    for (int i = tid; i < 64 * (D / 8); i += 256) {
        int j = i / (D / 8), d8 = (i % (D / 8)) * 8;
        const float4* wp = (const float4*)&W[j * D + d8];
        float4 w0 = wp[0], w1 = wp[1];
        h8 h = { (_Float16)w0.x, (_Float16)w0.y, (_Float16)w0.z, (_Float16)w0.w,
                 (_Float16)w1.x, (_Float16)w1.y, (_Float16)w1.z, (_Float16)w1.w };
        *(h8*)&Wh[j * RS + d8] = h;
    }
    for (int i = tid; i < 64 * (D / 8); i += 256) {
        int nl = i / (D / 8), d8 = (i % (D / 8)) * 8;
        int n = n0 + nl; if (n >= n_nodes) n = n_nodes - 1;
        const float4* xp = (const float4*)&X[(size_t)n * D + d8];
        float4 x0 = xp[0], x1 = xp[1];
        h8 h = { (_Float16)x0.x, (_Float16)x0.y, (_Float16)x0.z, (_Float16)x0.w,
                 (_Float16)x1.x, (_Float16)x1.y, (_Float16)x1.z, (_Float16)x1.w };
        *(h8*)&Xh[nl * RS + d8] = h;
    }
    __syncthreads();

    const int wid = tid >> 6, lane = tid & 63;
    const int lm = lane & 15, lq = lane >> 4;
    const int mBase = wid * 16;

    h8 bfrag[4][KS];
    #pragma unroll
    for (int t = 0; t < 4; ++t)
        #pragma unroll
        for (int s = 0; s < KS; ++s)
            bfrag[t][s] = *(const h8*)&Wh[(t * 16 + lm) * RS + s * 32 + lq * 8];

    // byp tile: rows lm<3 of bypW [3x128], zero otherwise (L1-hot, 1.5 KB)
    h8 bfragB[KS];
    #pragma unroll
    for (int s = 0; s < KS; ++s) {
        if (lm < 3) {
            const float4* wp = (const float4*)&bypW[lm * D + s * 32 + lq * 8];
            float4 w0 = wp[0], w1 = wp[1];
            bfragB[s] = (h8){ (_Float16)w0.x, (_Float16)w0.y, (_Float16)w0.z, (_Float16)w0.w,
                              (_Float16)w1.x, (_Float16)w1.y, (_Float16)w1.z, (_Float16)w1.w };
        } else {
            bfragB[s] = (h8)(_Float16)0;
        }
    }

    f32x4 acc[5] = {};
    #pragma unroll
    for (int s = 0; s < KS; ++s) {
        h8 a = *(const h8*)&Xh[(mBase + lm) * RS + s * 32 + lq * 8];
        #pragma unroll
        for (int t = 0; t < 4; ++t)
            acc[t] = __builtin_amdgcn_mfma_f32_16x16x32_f16(a, bfrag[t][s], acc[t], 0, 0, 0);
        acc[4] = __builtin_amdgcn_mfma_f32_16x16x32_f16(a, bfragB[s], acc[4], 0, 0, 0);
    }

    float bb[4];
    #pragma unroll
    for (int t = 0; t < 4; ++t) bb[t] = bias[t * 16 + lm];
    float bypbv = (lm < 3) ? bypb[lm] : 0.f;
    const int nodeBase = n0 + mBase + lq * 4;
    #pragma unroll
    for (int r = 0; r < 4; ++r) {
        int node = nodeBase + r;
        if (node < n_nodes) {
            #pragma unroll
            for (int t = 0; t < 4; ++t)
                Yh[(size_t)node * 64 + t * 16 + lm] = (_Float16)(acc[t][r] + bb[t]);
            if (lm < 3)
                bypOut[node * 3 + lm] = acc[4][r] + bypbv;
        }
    }
}

// ---------------- conv GEMM (D=64): fp16 A straight copy, Wh LDS, out fp16 * dinv ----------------
__global__ __launch_bounds__(256) void k_gemmC(const _Float16* __restrict__ Xhg,
                                               const float* __restrict__ W,
                                               const float* __restrict__ dinv,
                                               _Float16* __restrict__ Yh,
                                               int n_nodes) {
    constexpr int D = 64, RS = D + 8, KS = D / 32;
    __shared__ _Float16 Xh[64 * RS];     // 9.2 KB
    __shared__ _Float16 Wh[64 * RS];     // 9.2 KB
    const int tid = threadIdx.x;
    const int n0 = blockIdx.x * 64;

    for (int i = tid; i < 64 * (D / 8); i += 256) {
        int j = i / (D / 8), d8 = (i % (D / 8)) * 8;
        const float4* wp = (const float4*)&W[j * D + d8];
        float4 w0 = wp[0], w1 = wp[1];
        h8 h = { (_Float16)w0.x, (_Float16)w0.y, (_Float16)w0.z, (_Float16)w0.w,
                 (_Float16)w1.x, (_Float16)w1.y, (_Float16)w1.z, (_Float16)w1.w };
        *(h8*)&Wh[j * RS + d8] = h;
    }
    for (int i = tid; i < 64 * (D / 8); i += 256) {
        int nl = i / (D / 8), d8 = (i % (D / 8)) * 8;
        int n = n0 + nl; if (n >= n_nodes) n = n_nodes - 1;
        *(h8*)&Xh[nl * RS + d8] = *(const h8*)&Xhg[(size_t)n * D + d8];   // straight copy
    }
    __syncthreads();

    const int wid = tid >> 6, lane = tid & 63;
    const int lm = lane & 15, lq = lane >> 4;
    const int mBase = wid * 16;

    h8 bfrag[4][KS];
    #pragma unroll
    for (int t = 0; t < 4; ++t)
        #pragma unroll
        for (int s = 0; s < KS; ++s)
            bfrag[t][s] = *(const h8*)&Wh[(t * 16 + lm) * RS + s * 32 + lq * 8];

    f32x4 acc[4] = {};
    #pragma unroll
    for (int s = 0; s < KS; ++s) {
        h8 a = *(const h8*)&Xh[(mBase + lm) * RS + s * 32 + lq * 8];
        #pragma unroll
        for (int t = 0; t < 4; ++t)
            acc[t] = __builtin_amdgcn_mfma_f32_16x16x32_f16(a, bfrag[t][s], acc[t], 0, 0, 0);
    }

    const int nodeBase = n0 + mBase + lq * 4;
    #pragma unroll
    for (int r = 0; r < 4; ++r) {
        int node = nodeBase + r;
        if (node < n_nodes) {
            float sdv = dinv[node];
            #pragma unroll
            for (int t = 0; t < 4; ++t)
                Yh[(size_t)node * 64 + t * 16 + lm] = (_Float16)(acc[t][r] * sdv);
        }
    }
}

// ---------------- pull-aggregation: 8 nodes/wave, 8 lanes/node; hA fp16 ----------------
template<bool RES, bool HEAD>
__global__ __launch_bounds__(256) void k_gather(const _Float16* __restrict__ hBh,
                                                const float* __restrict__ dinv,
                                                const int* __restrict__ off,
                                                const int* __restrict__ csr_row,
                                                const float* __restrict__ convb,
                                                const float* __restrict__ bng,
                                                const float* __restrict__ bnb,
                                                _Float16* __restrict__ hA,
                                                const float* __restrict__ byp,
                                                const float* __restrict__ headW,
                                                const float* __restrict__ headb,
                                                float* __restrict__ out) {
    __shared__ float HWs[HEAD ? 204 : 1];
    const int tid = threadIdx.x;
    if constexpr (HEAD) {
        for (int i = tid; i < 204; i += 256)
            HWs[i] = (i < 201) ? headW[i] : headb[i - 201];
        __syncthreads();
    }
    const int wid = tid >> 6, lane = tid & 63;
    const int n = blockIdx.x * 32 + wid * 8 + (lane >> 3);   // grid = NN/32 exactly
    const int oct = lane & 7;
    const int f0 = oct * 8;

    const int e0 = off[n], eEnd = off[n + 1];
    const int deg = eEnd - e0;
    int m = deg;
    #pragma unroll
    for (int mask = 8; mask < 64; mask <<= 1) {
        int o = __shfl_xor(m, mask, 64);
        m = (o > m) ? o : m;
    }

    h8 acch = *(const h8*)(hBh + ((size_t)n << 6) + f0);   // self-loop term
    const h8 zero = (h8)(_Float16)0;
    for (int it = 0; it < m; it += 2) {
        bool v0 = it < deg, v1 = it + 1 < deg;
        int i0 = e0 + it, i1 = i0 + 1;
        int r0 = csr_row[v0 ? i0 : 0];
        int r1 = csr_row[v1 ? i1 : 0];
        h8 raw0 = *(const h8*)(hBh + ((size_t)r0 << 6) + f0);
        h8 raw1 = *(const h8*)(hBh + ((size_t)r1 << 6) + f0);
        acch = acch + (v0 ? raw0 : zero);
        acch = acch + (v1 ? raw1 : zero);
    }

    const float dv = dinv[n];
    const float bnscale = rsqrtf(1.0f + 1e-5f);
    const float4 cb0 = *(const float4*)&convb[f0], cb1 = *(const float4*)&convb[f0 + 4];
    const float4 g0  = *(const float4*)&bng[f0],  g1  = *(const float4*)&bng[f0 + 4];
    const float4 b0_ = *(const float4*)&bnb[f0],  b1_ = *(const float4*)&bnb[f0 + 4];
    const float cb[8] = { cb0.x, cb0.y, cb0.z, cb0.w, cb1.x, cb1.y, cb1.z, cb1.w };
    const float gg[8] = { g0.x, g0.y, g0.z, g0.w, g1.x, g1.y, g1.z, g1.w };
    const float bb[8] = { b0_.x, b0_.y, b0_.z, b0_.w, b1_.x, b1_.y, b1_.z, b1_.w };
    float v[8];
    #pragma unroll
    for (int j = 0; j < 8; ++j)
        v[j] = fmaxf(((float)acch[j] * dv + cb[j]) * (gg[j] * bnscale) + bb[j], 0.0f);

    if constexpr (!HEAD) {
        size_t o = ((size_t)n << 6) + f0;
        if constexpr (RES) {
            h8 old = *(const h8*)&hA[o];
            #pragma unroll
            for (int j = 0; j < 8; ++j) v[j] += (float)old[j];
        }
        h8 res = { (_Float16)v[0], (_Float16)v[1], (_Float16)v[2], (_Float16)v[3],
                   (_Float16)v[4], (_Float16)v[5], (_Float16)v[6], (_Float16)v[7] };
        *(h8*)&hA[o] = res;
    } else {
        float p[3];
        #pragma unroll
        for (int o = 0; o < 3; ++o) {
            float t = 0.f;
            #pragma unroll
            for (int j = 0; j < 8; ++j) t += v[j] * HWs[o * 67 + f0 + j];
            p[o] = t;
        }
        #pragma unroll
        for (int mask = 1; mask < 8; mask <<= 1) {
            #pragma unroll
            for (int o = 0; o < 3; ++o) p[o] += __shfl_xor(p[o], mask, 64);
        }
        if (oct == 0) {
            float by0 = byp[n * 3], by1 = byp[n * 3 + 1], by2 = byp[n * 3 + 2];
            #pragma unroll
            for (int o = 0; o < 3; ++o)
                p[o] += by0 * HWs[o * 67 + 64] + by1 * HWs[o * 67 + 65] + by2 * HWs[o * 67 + 66]
                      + HWs[201 + o];
            float kappa = fminf(fmaxf(p[0] * 5.0f + 2.5f, 0.2f), 10.0f);
            float tau   = fminf(fmaxf(p[2] + 0.5f, 0.05f), 2.0f);
            out[(size_t)n * 3]     = kappa;
            out[(size_t)n * 3 + 1] = p[1];
            out[(size_t)n * 3 + 2] = tau;
        }
    }
}

extern "C" void kernel_launch(void* const* d_in, const int* in_sizes, int n_in,
                              void* d_out, int out_size, void* d_ws, size_t ws_size,
                              hipStream_t stream) {
    const float* x     = (const float*)d_in[0];
    const int*   ei    = (const int*)d_in[1];
    const int*   row   = ei;
    const int*   col   = ei + NE;
    const float* projW = (const float*)d_in[2];
    const float* projb = (const float*)d_in[3];
    const float* convW[3] = { (const float*)d_in[4], (const float*)d_in[8],  (const float*)d_in[12] };
    const float* convb[3] = { (const float*)d_in[5], (const float*)d_in[9],  (const float*)d_in[13] };
    const float* bng[3]   = { (const float*)d_in[6], (const float*)d_in[10], (const float*)d_in[14] };
    const float* bnb[3]   = { (const float*)d_in[7], (const float*)d_in[11], (const float*)d_in[15] };
    const float* bypW  = (const float*)d_in[16];
    const float* bypb  = (const float*)d_in[17];
    const float* headW = (const float*)d_in[18];
    const float* headb = (const float*)d_in[19];
    float* out = (float*)d_out;

    float*    ws   = (float*)d_ws;
    float*    dinv = ws;                                   // 102400 floats
    _Float16* hAh  = (_Float16*)(ws + 102400);             // NN*64 fp16
    _Float16* hBh  = hAh + (size_t)NN * 64;                // NN*64 fp16
    float*    byp  = (float*)(hBh + (size_t)NN * 64);      // NN*3 (+pad)
    int*      off     = (int*)(byp + 300032);              // NN+1 (pad 100096)
    int*      csr_row = off + 100096;                      // NE
    int*      bcnt    = csr_row + NE;                      // NBUK+1 (pad 784)
    int*      bcur    = bcnt + 784;                        // NBUK
    unsigned* tmp     = (unsigned*)hAh;                    // aliases hAh (consumed before proj)

    // bucketed CSR build (+dinv +off)
    k_zerob<<<1, 1024, 0, stream>>>(bcnt);
    k_bhist<<<256, 256, 0, stream>>>(col, bcnt);
    k_bscan<<<1, 1024, 0, stream>>>(bcnt, bcur);
    k_bucket<<<NCHUNK, 256, 0, stream>>>(row, col, bcur, tmp);
    k_build<<<NBUK, 256, 0, stream>>>(tmp, bcnt, off, dinv, csr_row);

    // proj: hAh = fp16(x @ projW.T + projb), byp = x @ bypW.T + bypb (fused MFMA tile)
    k_gemmP<<<(NN + 63) / 64, 256, 0, stream>>>(x, projW, projb, hAh, bypW, bypb, byp, NN);

    for (int l = 0; l < 3; l++) {
        // hBh = fp16((hAh @ convW.T) * dinv)
        k_gemmC<<<(NN + 63) / 64, 256, 0, stream>>>(hAh, convW[l], dinv, hBh, NN);
        if (l < 2)
            k_gather<true, false><<<NN / 32, 256, 0, stream>>>(
                hBh, dinv, off, csr_row, convb[l], bng[l], bnb[l], hAh,
                nullptr, nullptr, nullptr, nullptr);
        else
            k_gather<false, true><<<NN / 32, 256, 0, stream>>>(
                hBh, dinv, off, csr_row, convb[l], bng[l], bnb[l], nullptr,
                byp, headW, headb, out);
    }
}